// Round 2
// baseline (1618.074 us; speedup 1.0000x reference)
//
#include <hip/hip_runtime.h>
#include <hip/hip_bf16.h>

#define F 256
#define H 256

__device__ __forceinline__ float bfbits2f(unsigned short u) {
    return __uint_as_float(((unsigned)u) << 16);
}

// K0: detect whether float buffers are fp32 or bf16.
// If buffer is fp32, even-indexed bf16-interpreted elements are mantissa
// garbage (uniform 16-bit patterns) -> some |v| >= 100 among 64 samples
// with overwhelming probability. If true bf16 (~N(0,1)), all |v| < 6.
__global__ void detect_kernel(const void* __restrict__ x_all, int* __restrict__ flag) {
    int lane = threadIdx.x;  // 64 threads
    unsigned short u = ((const unsigned short*)x_all)[lane * 2];
    float v = bfbits2f(u);
    bool bad = !(fabsf(v) < 100.0f);  // true for NaN as well
    unsigned long long m = __ballot(bad);
    if (lane == 0) *flag = (m != 0ULL) ? 1 : 0;
}

// K1: agg[n][:] = x[n_id[n]][:] (self-loop term), cnt[n] = 1
__global__ void init_kernel(const void* __restrict__ x_all,
                            const int* __restrict__ n_id,
                            float* __restrict__ agg,
                            float* __restrict__ cnt,
                            const int* __restrict__ flag,
                            int N) {
    int fp32m = *flag;
    int n = blockIdx.x;
    if (n >= N) return;
    int f = threadIdx.x;
    int row = n_id[n];
    size_t idx = (size_t)row * F + f;
    float v = fp32m ? ((const float*)x_all)[idx]
                    : bfbits2f(((const unsigned short*)x_all)[idx]);
    agg[(size_t)n * F + f] = v;
    if (f == 0) cnt[n] = 1.0f;
}

// K2: for each edge e: agg[dst[e]][:] += x[n_id[src[e]]][:]; cnt[dst[e]] += 1
// 64 lanes per edge, 4 floats per lane (4 edges per 256-thread block).
__global__ void edge_kernel(const void* __restrict__ x_all,
                            const int* __restrict__ n_id,
                            const int* __restrict__ src,
                            const int* __restrict__ dst,
                            float* __restrict__ agg,
                            float* __restrict__ cnt,
                            const int* __restrict__ flag,
                            int E) {
    int fp32m = *flag;
    int e = blockIdx.x * 4 + (threadIdx.x >> 6);
    if (e >= E) return;
    int lane = threadIdx.x & 63;
    int s = src[e];
    int d = dst[e];
    int row = n_id[s];

    float a0, a1, a2, a3;
    if (fp32m) {
        const float4* xs = reinterpret_cast<const float4*>(
            (const float*)x_all + (size_t)row * F + lane * 4);
        float4 v = *xs;
        a0 = v.x; a1 = v.y; a2 = v.z; a3 = v.w;
    } else {
        const ushort4* xs = reinterpret_cast<const ushort4*>(
            (const unsigned short*)x_all + (size_t)row * F + lane * 4);
        ushort4 v = *xs;
        a0 = bfbits2f(v.x); a1 = bfbits2f(v.y); a2 = bfbits2f(v.z); a3 = bfbits2f(v.w);
    }

    float* ad = agg + (size_t)d * F + lane * 4;
    atomicAdd(ad + 0, a0);
    atomicAdd(ad + 1, a1);
    atomicAdd(ad + 2, a2);
    atomicAdd(ad + 3, a3);
    if (lane == 0) atomicAdd(cnt + d, 1.0f);
}

// K3: per node n: xin = agg[n]/cnt[n]; h = xin @ W_sage + b_sage;
//     scores = h @ W_cls^T + b_cls; out = log_softmax(scores)
__global__ void node_kernel(const float* __restrict__ agg,
                            const float* __restrict__ cnt,
                            const void* __restrict__ W_sage,
                            const void* __restrict__ b_sage,
                            const void* __restrict__ W_cls,
                            const void* __restrict__ b_cls,
                            void* __restrict__ out,
                            const int* __restrict__ flag,
                            int N) {
    __shared__ float xin[F];
    __shared__ float red[3][4];

    int fp32m = *flag;
    int n = blockIdx.x;
    if (n >= N) return;
    int j = threadIdx.x;

    float inv = 1.0f / cnt[n];
    xin[j] = agg[(size_t)n * F + j] * inv;
    __syncthreads();

    float h, p0, p1, p2;
    if (fp32m) {
        const float* Wf = (const float*)W_sage;
        h = ((const float*)b_sage)[j];
        #pragma unroll 8
        for (int f = 0; f < F; ++f) {
            h = fmaf(xin[f], Wf[f * H + j], h);
        }
        const float* Wc = (const float*)W_cls;
        p0 = h * Wc[0 * H + j];
        p1 = h * Wc[1 * H + j];
        p2 = h * Wc[2 * H + j];
    } else {
        const unsigned short* Wf = (const unsigned short*)W_sage;
        h = bfbits2f(((const unsigned short*)b_sage)[j]);
        #pragma unroll 8
        for (int f = 0; f < F; ++f) {
            h = fmaf(xin[f], bfbits2f(Wf[f * H + j]), h);
        }
        const unsigned short* Wc = (const unsigned short*)W_cls;
        p0 = h * bfbits2f(Wc[0 * H + j]);
        p1 = h * bfbits2f(Wc[1 * H + j]);
        p2 = h * bfbits2f(Wc[2 * H + j]);
    }

    #pragma unroll
    for (int off = 32; off > 0; off >>= 1) {
        p0 += __shfl_down(p0, off);
        p1 += __shfl_down(p1, off);
        p2 += __shfl_down(p2, off);
    }
    int wave = j >> 6;
    if ((j & 63) == 0) {
        red[0][wave] = p0;
        red[1][wave] = p1;
        red[2][wave] = p2;
    }
    __syncthreads();

    if (j == 0) {
        float bc0, bc1, bc2;
        if (fp32m) {
            bc0 = ((const float*)b_cls)[0];
            bc1 = ((const float*)b_cls)[1];
            bc2 = ((const float*)b_cls)[2];
        } else {
            bc0 = bfbits2f(((const unsigned short*)b_cls)[0]);
            bc1 = bfbits2f(((const unsigned short*)b_cls)[1]);
            bc2 = bfbits2f(((const unsigned short*)b_cls)[2]);
        }
        float s0 = red[0][0] + red[0][1] + red[0][2] + red[0][3] + bc0;
        float s1 = red[1][0] + red[1][1] + red[1][2] + red[1][3] + bc1;
        float s2 = red[2][0] + red[2][1] + red[2][2] + red[2][3] + bc2;
        float m = fmaxf(s0, fmaxf(s1, s2));
        float lse = m + logf(expf(s0 - m) + expf(s1 - m) + expf(s2 - m));
        if (fp32m) {
            float* o = (float*)out;
            o[n * 3 + 0] = s0 - lse;
            o[n * 3 + 1] = s1 - lse;
            o[n * 3 + 2] = s2 - lse;
        } else {
            __hip_bfloat16* o = (__hip_bfloat16*)out;
            o[n * 3 + 0] = __float2bfloat16(s0 - lse);
            o[n * 3 + 1] = __float2bfloat16(s1 - lse);
            o[n * 3 + 2] = __float2bfloat16(s2 - lse);
        }
    }
}

extern "C" void kernel_launch(void* const* d_in, const int* in_sizes, int n_in,
                              void* d_out, int out_size, void* d_ws, size_t ws_size,
                              hipStream_t stream) {
    const void* x_all  = d_in[0];
    const int*  n_id   = (const int*)d_in[1];
    const int*  eidx   = (const int*)d_in[2];
    const void* W_sage = d_in[3];
    const void* b_sage = d_in[4];
    const void* W_cls  = d_in[5];
    const void* b_cls  = d_in[6];

    int N = in_sizes[1];
    int E = in_sizes[2] / 2;
    const int* src = eidx;
    const int* dst = eidx + E;

    // workspace layout: agg [N*F] fp32, cnt [N] fp32, flag [1] int
    float* agg = (float*)d_ws;
    float* cnt = agg + (size_t)N * F;
    int* flag = (int*)(cnt + N);

    detect_kernel<<<1, 64, 0, stream>>>(x_all, flag);
    init_kernel<<<N, F, 0, stream>>>(x_all, n_id, agg, cnt, flag, N);
    edge_kernel<<<(E + 3) / 4, 256, 0, stream>>>(x_all, n_id, src, dst, agg, cnt, flag, E);
    node_kernel<<<N, F, 0, stream>>>(agg, cnt, W_sage, b_sage, W_cls, b_cls, d_out, flag, N);
}

// Round 3
// 419.924 us; speedup vs baseline: 3.8533x; 3.8533x over previous
//
#include <hip/hip_runtime.h>
#include <hip/hip_bf16.h>

#define F 256
#define H 256
#define G 16   // nodes per block in fused kernel

__device__ __forceinline__ float bfbits2f(unsigned short u) {
    return __uint_as_float(((unsigned)u) << 16);
}

__device__ __forceinline__ float4 loadx4(const void* __restrict__ x, int row, int lane, int fp32m) {
    if (fp32m) {
        return ((const float4*)x)[(size_t)row * (F / 4) + lane];
    } else {
        ushort4 u = ((const ushort4*)x)[(size_t)row * (F / 4) + lane];
        return make_float4(bfbits2f(u.x), bfbits2f(u.y), bfbits2f(u.z), bfbits2f(u.w));
    }
}

__device__ __forceinline__ float loadw(const void* __restrict__ w, int idx, int fp32m) {
    return fp32m ? ((const float*)w)[idx] : bfbits2f(((const unsigned short*)w)[idx]);
}

// K0: detect fp32 vs bf16 input encoding (see round-1 notes).
__global__ void detect_kernel(const void* __restrict__ x_all, int* __restrict__ flag) {
    int lane = threadIdx.x;  // 64
    unsigned short u = ((const unsigned short*)x_all)[lane * 2];
    float v = bfbits2f(u);
    bool bad = !(fabsf(v) < 100.0f);
    unsigned long long m = __ballot(bad);
    if (lane == 0) *flag = (m != 0ULL) ? 1 : 0;
}

__global__ void zero_kernel(int* __restrict__ p, int n) {
    int i = blockIdx.x * blockDim.x + threadIdx.x;
    if (i < n) p[i] = 0;
}

__global__ void hist_kernel(const int* __restrict__ dst, int* __restrict__ deg, int E) {
    int e = blockIdx.x * blockDim.x + threadIdx.x;
    if (e < E) atomicAdd(&deg[dst[e]], 1);
}

// Exclusive scan of deg -> row_ptr[0..N], cur[i] = row start. One block, 1024 threads.
__global__ void scan_kernel(const int* __restrict__ deg, int* __restrict__ row_ptr,
                            int* __restrict__ cur, int N) {
    __shared__ int wsum[16];
    __shared__ int base;
    int tid = threadIdx.x;
    int lane = tid & 63, w = tid >> 6;
    if (tid == 0) { base = 0; row_ptr[0] = 0; }
    __syncthreads();
    for (int start = 0; start < N; start += 1024) {
        int i = start + tid;
        int v = (i < N) ? deg[i] : 0;
        int s = v;
        #pragma unroll
        for (int off = 1; off < 64; off <<= 1) {
            int t = __shfl_up(s, off);
            if (lane >= off) s += t;
        }
        if (lane == 63) wsum[w] = s;
        __syncthreads();
        if (tid == 0) {
            int acc = 0;
            #pragma unroll
            for (int k = 0; k < 16; ++k) { int t = wsum[k]; wsum[k] = acc; acc += t; }
        }
        __syncthreads();
        int excl = base + wsum[w] + s - v;
        if (i < N) { row_ptr[i + 1] = excl + v; cur[i] = excl; }
        __syncthreads();
        if (tid == 1023) base += wsum[15] + s;   // chunk total
        __syncthreads();
    }
}

__global__ void fill_kernel(const int* __restrict__ src, const int* __restrict__ dst,
                            int* __restrict__ cur, int* __restrict__ csr_src, int E) {
    int e = blockIdx.x * blockDim.x + threadIdx.x;
    if (e < E) {
        int d = dst[e];
        int p = atomicAdd(&cur[d], 1);
        csr_src[p] = src[e];
    }
}

// Fused: mean-aggregate (gather via CSR) -> xin in LDS -> h = xin@W_sage+b ->
// scores = h@W_cls^T + b_cls -> log_softmax -> out. 16 nodes per block.
__global__ __launch_bounds__(256) void fused_node(
        const void* __restrict__ x_all,
        const int* __restrict__ n_id,
        const int* __restrict__ row_ptr,
        const int* __restrict__ csr_src,
        const void* __restrict__ W_sage,
        const void* __restrict__ b_sage,
        const void* __restrict__ W_cls,
        const void* __restrict__ b_cls,
        void* __restrict__ out,
        const int* __restrict__ flag,
        int N) {
    __shared__ __align__(16) float xin[G][F];  // 16 KB; reused for h in epilogue
    __shared__ float sc[G][3];

    int fp32m = *flag;
    int n0 = blockIdx.x * G;
    int j = threadIdx.x;
    int w = j >> 6, lane = j & 63;

    // Phase 1: each wave aggregates 4 nodes; lane holds features lane*4..lane*4+3.
    for (int g = w; g < G; g += 4) {
        int n = n0 + g;
        if (n < N) {
            int r0 = row_ptr[n], r1 = row_ptr[n + 1];
            int row = n_id[n];
            float4 acc = loadx4(x_all, row, lane, fp32m);
            for (int e = r0; e < r1; ++e) {
                int srow = n_id[csr_src[e]];
                float4 v = loadx4(x_all, srow, lane, fp32m);
                acc.x += v.x; acc.y += v.y; acc.z += v.z; acc.w += v.w;
            }
            float inv = 1.0f / (float)(r1 - r0 + 1);
            acc.x *= inv; acc.y *= inv; acc.z *= inv; acc.w *= inv;
            *(float4*)&xin[g][lane * 4] = acc;
        }
    }
    __syncthreads();

    // Phase 2: thread j owns output column j for all G nodes.
    float h[G];
    #pragma unroll
    for (int g = 0; g < G; ++g) h[g] = loadw(b_sage, j, fp32m);

    for (int fb = 0; fb < F; fb += 4) {
        float w0 = loadw(W_sage, (fb + 0) * H + j, fp32m);
        float w1 = loadw(W_sage, (fb + 1) * H + j, fp32m);
        float w2 = loadw(W_sage, (fb + 2) * H + j, fp32m);
        float w3 = loadw(W_sage, (fb + 3) * H + j, fp32m);
        #pragma unroll
        for (int g = 0; g < G; ++g) {
            float4 xv = *(const float4*)&xin[g][fb];
            h[g] = fmaf(xv.x, w0, fmaf(xv.y, w1, fmaf(xv.z, w2, fmaf(xv.w, w3, h[g]))));
        }
    }
    __syncthreads();   // all xin reads done

    // Stash h into LDS (reuse xin): h_lds[g][j]
    #pragma unroll
    for (int g = 0; g < G; ++g) xin[g][j] = h[g];
    __syncthreads();

    // Classifier: 48 threads, one (g,c) each; skewed column walk to spread banks.
    if (j < 48) {
        int g = j / 3, c = j % 3;
        float sum = loadw(b_cls, c, fp32m);
        for (int i = 0; i < F; ++i) {
            int col = (i + j * 5) & (F - 1);
            sum = fmaf(xin[g][col], loadw(W_cls, c * H + col, fp32m), sum);
        }
        sc[g][c] = sum;
    }
    __syncthreads();

    // log_softmax + store: 16 threads, one node each.
    if (j < G && (n0 + j) < N) {
        float s0 = sc[j][0], s1 = sc[j][1], s2 = sc[j][2];
        float m = fmaxf(s0, fmaxf(s1, s2));
        float lse = m + logf(expf(s0 - m) + expf(s1 - m) + expf(s2 - m));
        int n = n0 + j;
        if (fp32m) {
            float* o = (float*)out;
            o[n * 3 + 0] = s0 - lse;
            o[n * 3 + 1] = s1 - lse;
            o[n * 3 + 2] = s2 - lse;
        } else {
            __hip_bfloat16* o = (__hip_bfloat16*)out;
            o[n * 3 + 0] = __float2bfloat16(s0 - lse);
            o[n * 3 + 1] = __float2bfloat16(s1 - lse);
            o[n * 3 + 2] = __float2bfloat16(s2 - lse);
        }
    }
}

extern "C" void kernel_launch(void* const* d_in, const int* in_sizes, int n_in,
                              void* d_out, int out_size, void* d_ws, size_t ws_size,
                              hipStream_t stream) {
    const void* x_all  = d_in[0];
    const int*  n_id   = (const int*)d_in[1];
    const int*  eidx   = (const int*)d_in[2];
    const void* W_sage = d_in[3];
    const void* b_sage = d_in[4];
    const void* W_cls  = d_in[5];
    const void* b_cls  = d_in[6];

    int N = in_sizes[1];
    int E = in_sizes[2] / 2;
    const int* src = eidx;
    const int* dst = eidx + E;

    // ws layout (ints): deg[N], cur[N], row_ptr[N+1], csr_src[E], flag[1]
    int* deg     = (int*)d_ws;
    int* cur     = deg + N;
    int* row_ptr = cur + N;
    int* csr_src = row_ptr + (N + 1);
    int* flag    = csr_src + E;

    detect_kernel<<<1, 64, 0, stream>>>(x_all, flag);
    zero_kernel<<<(N + 255) / 256, 256, 0, stream>>>(deg, N);
    hist_kernel<<<(E + 255) / 256, 256, 0, stream>>>(dst, deg, E);
    scan_kernel<<<1, 1024, 0, stream>>>(deg, row_ptr, cur, N);
    fill_kernel<<<(E + 255) / 256, 256, 0, stream>>>(src, dst, cur, csr_src, E);
    fused_node<<<(N + G - 1) / G, 256, 0, stream>>>(
        x_all, n_id, row_ptr, csr_src, W_sage, b_sage, W_cls, b_cls,
        d_out, flag, N);
}

// Round 4
// 374.001 us; speedup vs baseline: 4.3264x; 1.1228x over previous
//
#include <hip/hip_runtime.h>
#include <hip/hip_bf16.h>

#define F 256
#define H 256
#define G 16          // nodes per block in fused kernel
#define ROWE (F + 8)  // LDS row stride (bf16 elems): +8 kills 16-way bank conflicts

typedef __attribute__((ext_vector_type(8))) short bf16x8;
typedef __attribute__((ext_vector_type(4))) float f32x4;

__device__ __forceinline__ float bfbits2f(unsigned short u) {
    return __uint_as_float(((unsigned)u) << 16);
}
__device__ __forceinline__ unsigned short f2bf(float f) {   // RNE
    unsigned u = __float_as_uint(f);
    u += 0x7fff + ((u >> 16) & 1);
    return (unsigned short)(u >> 16);
}
__device__ __forceinline__ float loadw(const void* __restrict__ w, int idx, int fp32m) {
    return fp32m ? ((const float*)w)[idx] : bfbits2f(((const unsigned short*)w)[idx]);
}

// K0: fp32-vs-bf16 buffer encoding probe (values are bf16-rounded either way;
// this detects the STORAGE width — round-2/3 evidence: fp32 storage).
__global__ void detect_kernel(const void* __restrict__ x_all, int* __restrict__ flag) {
    int lane = threadIdx.x;  // 64
    unsigned short u = ((const unsigned short*)x_all)[lane * 2];
    float v = bfbits2f(u);
    bool bad = !(fabsf(v) < 100.0f);
    unsigned long long m = __ballot(bad);
    if (lane == 0) *flag = (m != 0ULL) ? 1 : 0;
}

__global__ void zero_kernel(int* __restrict__ p, int n) {
    int i = blockIdx.x * blockDim.x + threadIdx.x;
    if (i < n) p[i] = 0;
}

__global__ void hist_kernel(const int* __restrict__ dst, int* __restrict__ deg, int E) {
    int e = blockIdx.x * blockDim.x + threadIdx.x;
    if (e < E) atomicAdd(&deg[dst[e]], 1);
}

// Order-free CSR reservation: start[n] = fetch_add(total, deg[n]); cur[n]=start[n].
// Row placement order is arbitrary — aggregation is commutative.
__global__ void reserve_kernel(const int* __restrict__ deg, int* __restrict__ start,
                               int* __restrict__ cur, int* __restrict__ total, int N) {
    int n = blockIdx.x * blockDim.x + threadIdx.x;
    if (n < N) {
        int s = atomicAdd(total, deg[n]);
        start[n] = s;
        cur[n] = s;
    }
}

__global__ void fill_kernel(const int* __restrict__ src, const int* __restrict__ dst,
                            int* __restrict__ cur, int* __restrict__ csr_src, int E) {
    int e = blockIdx.x * blockDim.x + threadIdx.x;
    if (e < E) {
        int p = atomicAdd(&cur[dst[e]], 1);
        csr_src[p] = src[e];
    }
}

// Pre-gather sampled rows to bf16: xs[n][f] = bf16(x_all[n_id[n]][f]).
// Halves gather traffic and removes n_id indirection from the edge loop.
__global__ void prep_x(const void* __restrict__ x_all, const int* __restrict__ n_id,
                       unsigned short* __restrict__ xs, const int* __restrict__ flag, int N) {
    int fp32m = *flag;
    int n = blockIdx.x;
    int f = threadIdx.x;
    int row = n_id[n];
    size_t si = (size_t)row * F + f;
    unsigned short v = fp32m ? f2bf(((const float*)x_all)[si])
                             : ((const unsigned short*)x_all)[si];
    xs[(size_t)n * F + f] = v;
}

// Transpose W_sage -> Wt[j][f] bf16 (B-operand wants columns contiguous).
__global__ void prep_w(const void* __restrict__ W_sage, unsigned short* __restrict__ Wt,
                       const int* __restrict__ flag) {
    int fp32m = *flag;
    int j = blockIdx.x;   // output column of W = row of Wt
    int f = threadIdx.x;
    float v = loadw(W_sage, f * H + j, fp32m);
    Wt[(size_t)j * F + f] = f2bf(v);
}

// Fused: CSR mean-aggregate -> bf16 xin in LDS -> MFMA GEMM (h) -> classifier
// -> log_softmax. 16 nodes/block, 4 waves; wave w owns output cols [w*64,w*64+64).
__global__ __launch_bounds__(256) void fused_node(
        const unsigned short* __restrict__ xs,
        const int* __restrict__ deg,
        const int* __restrict__ start,
        const int* __restrict__ csr_src,
        const unsigned short* __restrict__ Wt,
        const void* __restrict__ b_sage,
        const void* __restrict__ W_cls,
        const void* __restrict__ b_cls,
        void* __restrict__ out,
        const int* __restrict__ flag,
        int N) {
    __shared__ __align__(16) unsigned short xin[G][ROWE];  // 8448 B (bf16 agg rows)
    __shared__ __align__(16) unsigned short hbf[G][ROWE];  // 8448 B (bf16 hidden)
    float (*red)[16][3] = (float (*)[16][3])&xin[0][0];    // overlay: xin dead by then

    int fp32m = *flag;
    int n0 = blockIdx.x * G;
    int t = threadIdx.x;
    int w = t >> 6, lane = t & 63;

    // ---- Phase 1: each wave mean-aggregates 4 nodes; lane owns feats lane*4..+3.
    for (int g = w; g < G; g += 4) {
        int n = n0 + g;
        if (n < N) {
            int d = deg[n], r0 = start[n];
            ushort4 v = ((const ushort4*)(xs + (size_t)n * F))[lane];
            float a0 = bfbits2f(v.x), a1 = bfbits2f(v.y),
                  a2 = bfbits2f(v.z), a3 = bfbits2f(v.w);
            int s_next = (d > 0) ? csr_src[r0] : 0;
            for (int e = 0; e < d; ++e) {
                int s = s_next;
                if (e + 1 < d) s_next = csr_src[r0 + e + 1];
                ushort4 u = ((const ushort4*)(xs + (size_t)s * F))[lane];
                a0 += bfbits2f(u.x); a1 += bfbits2f(u.y);
                a2 += bfbits2f(u.z); a3 += bfbits2f(u.w);
            }
            float inv = 1.0f / (float)(d + 1);
            ushort4 o;
            o.x = f2bf(a0 * inv); o.y = f2bf(a1 * inv);
            o.z = f2bf(a2 * inv); o.w = f2bf(a3 * inv);
            *(ushort4*)&xin[g][lane * 4] = o;
        }
    }
    __syncthreads();

    // ---- Phase 2: MFMA 16x16x32 bf16. A = xin (16 nodes x 256), B = Wt cols.
    // A-frag: A[m=lane&15][k=quad*8+j]; B-frag: B[n=lane&15][k=quad*8+j];
    // C/D: col=lane&15, row=quad*4+reg.
    int m = lane & 15, quad = lane >> 4;
    f32x4 acc[4];
    #pragma unroll
    for (int c = 0; c < 4; ++c) acc[c] = (f32x4){0.f, 0.f, 0.f, 0.f};

    #pragma unroll
    for (int ks = 0; ks < 8; ++ks) {
        bf16x8 a = *(const bf16x8*)&xin[m][ks * 32 + quad * 8];
        #pragma unroll
        for (int c = 0; c < 4; ++c) {
            int col = w * 64 + c * 16 + m;
            bf16x8 b = *(const bf16x8*)(Wt + (size_t)col * F + ks * 32 + quad * 8);
            acc[c] = __builtin_amdgcn_mfma_f32_16x16x32_bf16(a, b, acc[c], 0, 0, 0);
        }
    }

    // Epilogue: h = acc + b_sage, stash bf16 to LDS.
    #pragma unroll
    for (int c = 0; c < 4; ++c) {
        int col = w * 64 + c * 16 + m;
        float bs = loadw(b_sage, col, fp32m);
        #pragma unroll
        for (int r = 0; r < 4; ++r) {
            int node = quad * 4 + r;
            hbf[node][col] = f2bf(acc[c][r] + bs);
        }
    }
    __syncthreads();

    // ---- Phase 3: classifier. thread t=(g,i): partial dot over cols i*16..i*16+15.
    {
        int g = t >> 4, i = t & 15;
        bf16x8 h0 = *(const bf16x8*)&hbf[g][i * 16];
        bf16x8 h1 = *(const bf16x8*)&hbf[g][i * 16 + 8];
        float p0 = 0.f, p1 = 0.f, p2 = 0.f;
        #pragma unroll
        for (int jj = 0; jj < 8; ++jj) {
            int col = i * 16 + jj;
            float hv = bfbits2f((unsigned short)h0[jj]);
            p0 = fmaf(hv, loadw(W_cls, 0 * H + col, fp32m), p0);
            p1 = fmaf(hv, loadw(W_cls, 1 * H + col, fp32m), p1);
            p2 = fmaf(hv, loadw(W_cls, 2 * H + col, fp32m), p2);
        }
        #pragma unroll
        for (int jj = 0; jj < 8; ++jj) {
            int col = i * 16 + 8 + jj;
            float hv = bfbits2f((unsigned short)h1[jj]);
            p0 = fmaf(hv, loadw(W_cls, 0 * H + col, fp32m), p0);
            p1 = fmaf(hv, loadw(W_cls, 1 * H + col, fp32m), p1);
            p2 = fmaf(hv, loadw(W_cls, 2 * H + col, fp32m), p2);
        }
        red[g][i][0] = p0; red[g][i][1] = p1; red[g][i][2] = p2;
    }
    __syncthreads();

    // ---- Phase 4: reduce 16 partials, log_softmax, store. 16 threads.
    if (t < G && (n0 + t) < N) {
        float s0 = loadw(b_cls, 0, fp32m);
        float s1 = loadw(b_cls, 1, fp32m);
        float s2 = loadw(b_cls, 2, fp32m);
        #pragma unroll
        for (int i = 0; i < 16; ++i) {
            s0 += red[t][i][0]; s1 += red[t][i][1]; s2 += red[t][i][2];
        }
        float mx = fmaxf(s0, fmaxf(s1, s2));
        float lse = mx + logf(expf(s0 - mx) + expf(s1 - mx) + expf(s2 - mx));
        int n = n0 + t;
        if (fp32m) {
            float* o = (float*)out;
            o[n * 3 + 0] = s0 - lse; o[n * 3 + 1] = s1 - lse; o[n * 3 + 2] = s2 - lse;
        } else {
            __hip_bfloat16* o = (__hip_bfloat16*)out;
            o[n * 3 + 0] = __float2bfloat16(s0 - lse);
            o[n * 3 + 1] = __float2bfloat16(s1 - lse);
            o[n * 3 + 2] = __float2bfloat16(s2 - lse);
        }
    }
}

extern "C" void kernel_launch(void* const* d_in, const int* in_sizes, int n_in,
                              void* d_out, int out_size, void* d_ws, size_t ws_size,
                              hipStream_t stream) {
    const void* x_all  = d_in[0];
    const int*  n_id   = (const int*)d_in[1];
    const int*  eidx   = (const int*)d_in[2];
    const void* W_sage = d_in[3];
    const void* b_sage = d_in[4];
    const void* W_cls  = d_in[5];
    const void* b_cls  = d_in[6];

    int N = in_sizes[1];
    int E = in_sizes[2] / 2;
    const int* src = eidx;
    const int* dst = eidx + E;

    // ws layout: xs[N*F] bf16 | Wt[H*F] bf16 | deg[N] total[1] start[N] cur[N]
    //            csr_src[E] flag[1]   (~27.5 MB total; 51.4 MB proven available)
    unsigned short* xs = (unsigned short*)d_ws;
    unsigned short* Wt = xs + (size_t)N * F;
    int* deg     = (int*)(Wt + (size_t)H * F);
    int* total   = deg + N;
    int* start   = total + 1;
    int* cur     = start + N;
    int* csr_src = cur + N;
    int* flag    = csr_src + E;

    detect_kernel<<<1, 64, 0, stream>>>(x_all, flag);
    zero_kernel<<<(N + 1 + 255) / 256, 256, 0, stream>>>(deg, N + 1);  // deg + total
    hist_kernel<<<(E + 255) / 256, 256, 0, stream>>>(dst, deg, E);
    reserve_kernel<<<(N + 255) / 256, 256, 0, stream>>>(deg, start, cur, total, N);
    fill_kernel<<<(E + 255) / 256, 256, 0, stream>>>(src, dst, cur, csr_src, E);
    prep_x<<<N, F, 0, stream>>>(x_all, n_id, xs, flag, N);
    prep_w<<<H, F, 0, stream>>>(W_sage, Wt, flag);
    fused_node<<<(N + G - 1) / G, 256, 0, stream>>>(
        xs, deg, start, csr_src, Wt, b_sage, W_cls, b_cls, d_out, flag, N);
}

// Round 5
// 351.403 us; speedup vs baseline: 4.6046x; 1.0643x over previous
//
#include <hip/hip_runtime.h>
#include <hip/hip_bf16.h>

#define F 256
#define H 256
#define G 16          // nodes per block in fused kernel (MFMA M-tile)
#define CAP 64        // max neighbors stored per node (Poisson lambda=6 -> P(>64)~1e-44)
#define ROWE (F + 8)  // LDS row stride (bf16 elems)

typedef __attribute__((ext_vector_type(8))) short bf16x8;
typedef __attribute__((ext_vector_type(4))) float f32x4;

__device__ __forceinline__ float bfbits2f(unsigned short u) {
    return __uint_as_float(((unsigned)u) << 16);
}
__device__ __forceinline__ unsigned short f2bf(float f) {   // RNE
    unsigned u = __float_as_uint(f);
    u += 0x7fff + ((u >> 16) & 1);
    return (unsigned short)(u >> 16);
}
__device__ __forceinline__ float loadw(const void* __restrict__ w, int idx, int fp32m) {
    return fp32m ? ((const float*)w)[idx] : bfbits2f(((const unsigned short*)w)[idx]);
}

// K1: zero cnt[N] (+ last block probes fp32-vs-bf16 storage encoding).
__global__ void setup_kernel(const void* __restrict__ x_all, int* __restrict__ cnt,
                             int* __restrict__ flag, int N) {
    int b = blockIdx.x;
    int nzero = (N + 255) / 256;
    if (b < nzero) {
        int i = b * 256 + threadIdx.x;
        if (i < N) cnt[i] = 0;
    } else if (threadIdx.x < 64) {
        unsigned short u = ((const unsigned short*)x_all)[threadIdx.x * 2];
        float v = bfbits2f(u);
        bool bad = !(fabsf(v) < 100.0f);
        unsigned long long m = __ballot(bad);
        if (threadIdx.x == 0) *flag = (m != 0ULL) ? 1 : 0;
    }
}

// K2: fixed-capacity bucketing (replaces hist+scan/reserve+fill).
__global__ void fill_bucket(const int* __restrict__ src, const int* __restrict__ dst,
                            int* __restrict__ cnt, int* __restrict__ bucket, int E) {
    int e = blockIdx.x * blockDim.x + threadIdx.x;
    if (e < E) {
        int d = dst[e];
        int p = atomicAdd(&cnt[d], 1);
        if (p < CAP) bucket[(size_t)d * CAP + p] = src[e];
    }
}

// K3: blocks [0,N): xs[n][f] = bf16(x_all[n_id[n]][f]);
//     blocks [N,N+H): Wt[j][f] = bf16(W_sage[f*H + j])  (transpose for B-operand).
__global__ void prep_kernel(const void* __restrict__ x_all, const int* __restrict__ n_id,
                            const void* __restrict__ W_sage,
                            unsigned short* __restrict__ xs, unsigned short* __restrict__ Wt,
                            const int* __restrict__ flag, int N) {
    int fp32m = *flag;
    int b = blockIdx.x;
    int f = threadIdx.x;
    if (b < N) {
        int row = n_id[b];
        size_t si = (size_t)row * F + f;
        unsigned short v = fp32m ? f2bf(((const float*)x_all)[si])
                                 : ((const unsigned short*)x_all)[si];
        xs[(size_t)b * F + f] = v;
    } else {
        int j = b - N;
        Wt[(size_t)j * F + f] = f2bf(loadw(W_sage, f * H + j, fp32m));
    }
}

// K4: fused aggregate (bucket gather, 4 loads in flight) -> MFMA GEMM ->
// classifier -> log_softmax. 16 nodes/block, 4 waves; wave w owns cols [w*64, w*64+64).
__global__ __launch_bounds__(256) void fused_node(
        const unsigned short* __restrict__ xs,
        const int* __restrict__ cnt,
        const int* __restrict__ bucket,
        const unsigned short* __restrict__ Wt,
        const void* __restrict__ b_sage,
        const void* __restrict__ W_cls,
        const void* __restrict__ b_cls,
        void* __restrict__ out,
        const int* __restrict__ flag,
        int N) {
    __shared__ __align__(16) unsigned short xin[G][ROWE];  // bf16 aggregated rows
    __shared__ __align__(16) unsigned short hbf[G][ROWE];  // bf16 hidden rows
    float (*red)[16][3] = (float (*)[16][3])&xin[0][0];    // overlay: xin dead by phase 3

    int fp32m = *flag;
    int n0 = blockIdx.x * G;
    int t = threadIdx.x;
    int w = t >> 6, lane = t & 63;

    // ---- Phase 1: wave w mean-aggregates nodes w, w+4, w+8, w+12.
    // 4-wide unroll keeps 4 independent row loads in flight per latency wait.
    for (int g = w; g < G; g += 4) {
        int n = n0 + g;
        if (n < N) {
            int dtrue = cnt[n];
            int d = dtrue < CAP ? dtrue : CAP;
            const int* __restrict__ bk = bucket + (size_t)n * CAP;
            ushort4 v = ((const ushort4*)(xs + (size_t)n * F))[lane];
            float a0 = bfbits2f(v.x), a1 = bfbits2f(v.y),
                  a2 = bfbits2f(v.z), a3 = bfbits2f(v.w);
            for (int e = 0; e < d; e += 4) {
                int rem = d - e;
                int i0 = bk[e];
                int i1 = (rem > 1) ? bk[e + 1] : i0;
                int i2 = (rem > 2) ? bk[e + 2] : i0;
                int i3 = (rem > 3) ? bk[e + 3] : i0;
                ushort4 u0 = ((const ushort4*)(xs + (size_t)i0 * F))[lane];
                ushort4 u1 = ((const ushort4*)(xs + (size_t)i1 * F))[lane];
                ushort4 u2 = ((const ushort4*)(xs + (size_t)i2 * F))[lane];
                ushort4 u3 = ((const ushort4*)(xs + (size_t)i3 * F))[lane];
                a0 += bfbits2f(u0.x); a1 += bfbits2f(u0.y);
                a2 += bfbits2f(u0.z); a3 += bfbits2f(u0.w);
                if (rem > 1) { a0 += bfbits2f(u1.x); a1 += bfbits2f(u1.y);
                               a2 += bfbits2f(u1.z); a3 += bfbits2f(u1.w); }
                if (rem > 2) { a0 += bfbits2f(u2.x); a1 += bfbits2f(u2.y);
                               a2 += bfbits2f(u2.z); a3 += bfbits2f(u2.w); }
                if (rem > 3) { a0 += bfbits2f(u3.x); a1 += bfbits2f(u3.y);
                               a2 += bfbits2f(u3.z); a3 += bfbits2f(u3.w); }
            }
            float inv = 1.0f / (float)(dtrue + 1);
            ushort4 o;
            o.x = f2bf(a0 * inv); o.y = f2bf(a1 * inv);
            o.z = f2bf(a2 * inv); o.w = f2bf(a3 * inv);
            *(ushort4*)&xin[g][lane * 4] = o;
        }
    }
    __syncthreads();

    // ---- Phase 2: MFMA 16x16x32 bf16. A = xin (16 nodes x 256 k), B = Wt columns.
    // A-frag: A[m=lane&15][k=quad*8+j]; B-frag: B[n=lane&15][k=quad*8+j];
    // C/D: col=lane&15, row=quad*4+reg.
    int m = lane & 15, quad = lane >> 4;
    f32x4 acc[4];
    #pragma unroll
    for (int c = 0; c < 4; ++c) acc[c] = (f32x4){0.f, 0.f, 0.f, 0.f};

    #pragma unroll
    for (int ks = 0; ks < 8; ++ks) {
        bf16x8 a = *(const bf16x8*)&xin[m][ks * 32 + quad * 8];
        #pragma unroll
        for (int c = 0; c < 4; ++c) {
            int col = w * 64 + c * 16 + m;
            bf16x8 b = *(const bf16x8*)(Wt + (size_t)col * F + ks * 32 + quad * 8);
            acc[c] = __builtin_amdgcn_mfma_f32_16x16x32_bf16(a, b, acc[c], 0, 0, 0);
        }
    }

    // Epilogue: h = acc + b_sage -> bf16 LDS.
    #pragma unroll
    for (int c = 0; c < 4; ++c) {
        int col = w * 64 + c * 16 + m;
        float bs = loadw(b_sage, col, fp32m);
        #pragma unroll
        for (int r = 0; r < 4; ++r) {
            int node = quad * 4 + r;
            hbf[node][col] = f2bf(acc[c][r] + bs);
        }
    }
    __syncthreads();

    // ---- Phase 3: classifier partials. thread t=(g,i): cols i*16..i*16+15.
    {
        int g = t >> 4, i = t & 15;
        bf16x8 h0 = *(const bf16x8*)&hbf[g][i * 16];
        bf16x8 h1 = *(const bf16x8*)&hbf[g][i * 16 + 8];
        float p0 = 0.f, p1 = 0.f, p2 = 0.f;
        #pragma unroll
        for (int jj = 0; jj < 8; ++jj) {
            int col = i * 16 + jj;
            float hv = bfbits2f((unsigned short)h0[jj]);
            p0 = fmaf(hv, loadw(W_cls, 0 * H + col, fp32m), p0);
            p1 = fmaf(hv, loadw(W_cls, 1 * H + col, fp32m), p1);
            p2 = fmaf(hv, loadw(W_cls, 2 * H + col, fp32m), p2);
        }
        #pragma unroll
        for (int jj = 0; jj < 8; ++jj) {
            int col = i * 16 + 8 + jj;
            float hv = bfbits2f((unsigned short)h1[jj]);
            p0 = fmaf(hv, loadw(W_cls, 0 * H + col, fp32m), p0);
            p1 = fmaf(hv, loadw(W_cls, 1 * H + col, fp32m), p1);
            p2 = fmaf(hv, loadw(W_cls, 2 * H + col, fp32m), p2);
        }
        red[g][i][0] = p0; red[g][i][1] = p1; red[g][i][2] = p2;
    }
    __syncthreads();

    // ---- Phase 4: reduce, log_softmax, store.
    if (t < G && (n0 + t) < N) {
        float s0 = loadw(b_cls, 0, fp32m);
        float s1 = loadw(b_cls, 1, fp32m);
        float s2 = loadw(b_cls, 2, fp32m);
        #pragma unroll
        for (int i = 0; i < 16; ++i) {
            s0 += red[t][i][0]; s1 += red[t][i][1]; s2 += red[t][i][2];
        }
        float mx = fmaxf(s0, fmaxf(s1, s2));
        float lse = mx + logf(expf(s0 - mx) + expf(s1 - mx) + expf(s2 - mx));
        int n = n0 + t;
        if (fp32m) {
            float* o = (float*)out;
            o[n * 3 + 0] = s0 - lse; o[n * 3 + 1] = s1 - lse; o[n * 3 + 2] = s2 - lse;
        } else {
            __hip_bfloat16* o = (__hip_bfloat16*)out;
            o[n * 3 + 0] = __float2bfloat16(s0 - lse);
            o[n * 3 + 1] = __float2bfloat16(s1 - lse);
            o[n * 3 + 2] = __float2bfloat16(s2 - lse);
        }
    }
}

extern "C" void kernel_launch(void* const* d_in, const int* in_sizes, int n_in,
                              void* d_out, int out_size, void* d_ws, size_t ws_size,
                              hipStream_t stream) {
    const void* x_all  = d_in[0];
    const int*  n_id   = (const int*)d_in[1];
    const int*  eidx   = (const int*)d_in[2];
    const void* W_sage = d_in[3];
    const void* b_sage = d_in[4];
    const void* W_cls  = d_in[5];
    const void* b_cls  = d_in[6];

    int N = in_sizes[1];
    int E = in_sizes[2] / 2;
    const int* src = eidx;
    const int* dst = eidx + E;

    // ws: xs[N*F] bf16 | Wt[H*F] bf16 | cnt[N] int | bucket[N*CAP] int | flag[1]
    // = 25.6MB + 131KB + 200KB + 12.8MB + 4B ~= 38.8 MB (<= 51.4MB proven available)
    unsigned short* xs = (unsigned short*)d_ws;
    unsigned short* Wt = xs + (size_t)N * F;
    int* cnt    = (int*)(Wt + (size_t)H * F);
    int* bucket = cnt + N;
    int* flag   = bucket + (size_t)N * CAP;

    int nzero = (N + 255) / 256;
    setup_kernel<<<nzero + 1, 256, 0, stream>>>(x_all, cnt, flag, N);
    fill_bucket<<<(E + 255) / 256, 256, 0, stream>>>(src, dst, cnt, bucket, E);
    prep_kernel<<<N + H, F, 0, stream>>>(x_all, n_id, W_sage, xs, Wt, flag, N);
    fused_node<<<(N + G - 1) / G, 256, 0, stream>>>(
        xs, cnt, bucket, Wt, b_sage, W_cls, b_cls, d_out, flag, N);
}

// Round 6
// 264.814 us; speedup vs baseline: 6.1102x; 1.3270x over previous
//
#include <hip/hip_runtime.h>
#include <hip/hip_bf16.h>

#define F 256
#define CAP 63        // max neighbors kept per node (Poisson lambda=6 -> P(>63) ~ 1e-43)
// bucket row layout (64 ints, 256 B): [0]=cnt, [1..63]=neighbor ids

__device__ __forceinline__ float bfbits2f(unsigned short u) {
    return __uint_as_float(((unsigned)u) << 16);
}
__device__ __forceinline__ unsigned short f2bf(float f) {   // RNE
    unsigned u = __float_as_uint(f);
    u += 0x7fff + ((u >> 16) & 1);
    return (unsigned short)(u >> 16);
}
__device__ __forceinline__ float loadw(const void* __restrict__ w, int idx, int fp32m) {
    return fp32m ? ((const float*)w)[idx] : bfbits2f(((const unsigned short*)w)[idx]);
}

// K1: zero bucket cnt slots; last block probes fp32-vs-bf16 storage (r2-5: fp32).
__global__ void setup_kernel(const void* __restrict__ x_all, int* __restrict__ bucket,
                             int* __restrict__ flag, int N) {
    int b = blockIdx.x;
    int nzero = (N + 255) / 256;
    if (b < nzero) {
        int i = b * 256 + threadIdx.x;
        if (i < N) bucket[(size_t)i << 6] = 0;
    } else if (threadIdx.x < 64) {
        unsigned short u = ((const unsigned short*)x_all)[threadIdx.x * 2];
        float v = bfbits2f(u);
        bool bad = !(fabsf(v) < 100.0f);
        unsigned long long m = __ballot(bad);
        if (threadIdx.x == 0) *flag = (m != 0ULL) ? 1 : 0;
    }
}

// K2: bucket fill. cnt slot doubles as the atomic counter.
__global__ void fill_bucket(const int* __restrict__ src, const int* __restrict__ dst,
                            int* __restrict__ bucket, int E) {
    int e = blockIdx.x * blockDim.x + threadIdx.x;
    if (e < E) {
        int d = dst[e];
        int p = atomicAdd(&bucket[(size_t)d << 6], 1);
        if (p < CAP) bucket[((size_t)d << 6) + 1 + p] = src[e];
    }
}

// K3: blocks [0,N): xs[n] = bf16(x_all[n_id[n]]) (lossless: values bf16-rounded).
//     block N: composite Wc2[f] = float4(sum_j Ws[f][j]*Wc[c][j], c=0..2, 0)
//     block N+1: bc2[c] = sum_j bs[j]*Wc[c][j] + b_cls[c]
__global__ void prep_kernel(const void* __restrict__ x_all, const int* __restrict__ n_id,
                            const void* __restrict__ W_sage, const void* __restrict__ b_sage,
                            const void* __restrict__ W_cls, const void* __restrict__ b_cls,
                            unsigned short* __restrict__ xs, float4* __restrict__ Wc2,
                            float* __restrict__ bc2,
                            const int* __restrict__ flag, int N) {
    int fp32m = *flag;
    int b = blockIdx.x;
    int t = threadIdx.x;
    if (b < N) {
        int row = n_id[b];
        size_t si = (size_t)row * F + t;
        unsigned short v = fp32m ? f2bf(((const float*)x_all)[si])
                                 : ((const unsigned short*)x_all)[si];
        xs[(size_t)b * F + t] = v;
    } else if (b == N) {
        __shared__ float wc[3][F];
        #pragma unroll
        for (int c = 0; c < 3; ++c) wc[c][t] = loadw(W_cls, c * F + t, fp32m);
        __syncthreads();
        float s0 = 0.f, s1 = 0.f, s2 = 0.f;
        for (int j = 0; j < F; ++j) {
            float ws = loadw(W_sage, t * F + j, fp32m);   // W_sage[f=t][j]
            s0 = fmaf(ws, wc[0][j], s0);
            s1 = fmaf(ws, wc[1][j], s1);
            s2 = fmaf(ws, wc[2][j], s2);
        }
        Wc2[t] = make_float4(s0, s1, s2, 0.f);
    } else {
        __shared__ float r[4][3];
        int lane = t & 63, w = t >> 6;
        float bs = loadw(b_sage, t, fp32m);
        float p0 = bs * loadw(W_cls, 0 * F + t, fp32m);
        float p1 = bs * loadw(W_cls, 1 * F + t, fp32m);
        float p2 = bs * loadw(W_cls, 2 * F + t, fp32m);
        #pragma unroll
        for (int off = 32; off > 0; off >>= 1) {
            p0 += __shfl_xor(p0, off);
            p1 += __shfl_xor(p1, off);
            p2 += __shfl_xor(p2, off);
        }
        if (lane == 0) { r[w][0] = p0; r[w][1] = p1; r[w][2] = p2; }
        __syncthreads();
        if (t < 3) {
            bc2[t] = r[0][t] + r[1][t] + r[2][t] + r[3][t] + loadw(b_cls, t, fp32m);
        }
    }
}

// K4: one wave per node (grid-stride). Single 256 B adjacency load; all neighbor
// row loads independent; fp32 register accumulation; composite-weight dot;
// butterfly reduce; lanes 0-2 store log_softmax outputs.
__global__ __launch_bounds__(256) void final_kernel(
        const unsigned short* __restrict__ xs,
        const int* __restrict__ bucket,
        const float4* __restrict__ Wc2,
        const float* __restrict__ bc2,
        void* __restrict__ out,
        const int* __restrict__ flag,
        int N) {
    int fp32m = *flag;
    int lane = threadIdx.x & 63;
    int gw = (blockIdx.x * 256 + threadIdx.x) >> 6;
    int nw = gridDim.x * 4;

    // per-lane composite weights for features lane*4 .. lane*4+3 (held in regs)
    float4 w0 = Wc2[lane * 4 + 0];
    float4 w1 = Wc2[lane * 4 + 1];
    float4 w2 = Wc2[lane * 4 + 2];
    float4 w3 = Wc2[lane * 4 + 3];
    float b0 = bc2[0], b1 = bc2[1], b2 = bc2[2];

    for (int n = gw; n < N; n += nw) {
        int meta = bucket[((size_t)n << 6) + lane];     // lane0=cnt, lanes1..63=ids
        int dt = __shfl(meta, 0);
        int d = dt < CAP ? dt : CAP;

        // self row
        ushort4 u = ((const ushort4*)xs)[(size_t)n * 64 + lane];
        float a0 = bfbits2f(u.x), a1 = bfbits2f(u.y),
              a2 = bfbits2f(u.z), a3 = bfbits2f(u.w);
        // neighbor rows — addresses depend only on meta broadcast; loads pipeline
        for (int e = 0; e < d; ++e) {
            int idx = __shfl(meta, e + 1);
            ushort4 v = ((const ushort4*)xs)[(size_t)idx * 64 + lane];
            a0 += bfbits2f(v.x); a1 += bfbits2f(v.y);
            a2 += bfbits2f(v.z); a3 += bfbits2f(v.w);
        }
        float inv = 1.0f / (float)(dt + 1);

        float p0 = a0 * w0.x + a1 * w1.x + a2 * w2.x + a3 * w3.x;
        float p1 = a0 * w0.y + a1 * w1.y + a2 * w2.y + a3 * w3.y;
        float p2 = a0 * w0.z + a1 * w1.z + a2 * w2.z + a3 * w3.z;

        #pragma unroll
        for (int off = 32; off > 0; off >>= 1) {
            p0 += __shfl_xor(p0, off);
            p1 += __shfl_xor(p1, off);
            p2 += __shfl_xor(p2, off);
        }
        // every lane now has all three sums
        float s0 = p0 * inv + b0;
        float s1 = p1 * inv + b1;
        float s2 = p2 * inv + b2;
        if (lane < 3) {
            float mx = fmaxf(s0, fmaxf(s1, s2));
            float lse = mx + logf(expf(s0 - mx) + expf(s1 - mx) + expf(s2 - mx));
            float sc = (lane == 0) ? s0 : (lane == 1) ? s1 : s2;
            if (fp32m) ((float*)out)[(size_t)n * 3 + lane] = sc - lse;
            else ((__hip_bfloat16*)out)[(size_t)n * 3 + lane] = __float2bfloat16(sc - lse);
        }
    }
}

extern "C" void kernel_launch(void* const* d_in, const int* in_sizes, int n_in,
                              void* d_out, int out_size, void* d_ws, size_t ws_size,
                              hipStream_t stream) {
    const void* x_all  = d_in[0];
    const int*  n_id   = (const int*)d_in[1];
    const int*  eidx   = (const int*)d_in[2];
    const void* W_sage = d_in[3];
    const void* b_sage = d_in[4];
    const void* W_cls  = d_in[5];
    const void* b_cls  = d_in[6];

    int N = in_sizes[1];
    int E = in_sizes[2] / 2;
    const int* src = eidx;
    const int* dst = eidx + E;

    // ws: xs[N*F] bf16 (25.6MB) | bucket[N*64] int (12.8MB) | Wc2[256] float4 (4KB)
    //     | bc2[3] float | flag[1] int   -> ~38.5 MB
    unsigned short* xs = (unsigned short*)d_ws;
    int* bucket = (int*)(xs + (size_t)N * F);
    float4* Wc2 = (float4*)(bucket + ((size_t)N << 6));
    float* bc2  = (float*)(Wc2 + F);
    int* flag   = (int*)(bc2 + 4);

    int nzero = (N + 255) / 256;
    setup_kernel<<<nzero + 1, 256, 0, stream>>>(x_all, bucket, flag, N);
    fill_bucket<<<(E + 255) / 256, 256, 0, stream>>>(src, dst, bucket, E);
    prep_kernel<<<N + 2, 256, 0, stream>>>(x_all, n_id, W_sage, b_sage, W_cls, b_cls,
                                           xs, Wc2, bc2, flag, N);
    final_kernel<<<2048, 256, 0, stream>>>(xs, bucket, Wc2, bc2, d_out, flag, N);
}

// Round 7
// 249.723 us; speedup vs baseline: 6.4795x; 1.0604x over previous
//
#include <hip/hip_runtime.h>
#include <hip/hip_bf16.h>

#define F 256

__device__ __forceinline__ float bfbits2f(unsigned short u) {
    return __uint_as_float(((unsigned)u) << 16);
}
__device__ __forceinline__ float loadw(const void* __restrict__ w, int idx, int fp32m) {
    return fp32m ? ((const float*)w)[idx] : bfbits2f(((const unsigned short*)w)[idx]);
}
// local fp32-vs-bf16 storage probe (r2-r6 evidence: fp32 storage, bf16-rounded values)
__device__ __forceinline__ int probe_fp32(const void* __restrict__ x_all) {
    unsigned short u = ((const unsigned short*)x_all)[(threadIdx.x & 63) * 2];
    float v = bfbits2f(u);
    unsigned long long m = __ballot(!(fabsf(v) < 100.0f));
    return (m != 0ULL) ? 1 : 0;
}

// K1: blocks [0,nzero): zero acc[N*4]; block nzero: write global flag;
//     block nzero+1: composite Wc2[f][c] = sum_j Ws[f][j]*Wc[c][j];
//     block nzero+2: bc2[c] = sum_j bs[j]*Wc[c][j] + b_cls[c].
__global__ void setup_kernel(const void* __restrict__ x_all,
                             const void* __restrict__ W_sage, const void* __restrict__ b_sage,
                             const void* __restrict__ W_cls, const void* __restrict__ b_cls,
                             float* __restrict__ acc, float4* __restrict__ Wc2,
                             float* __restrict__ bc2, int* __restrict__ flag, int N) {
    int b = blockIdx.x;
    int t = threadIdx.x;
    int nzero = (N * 4 + 255) / 256;
    if (b < nzero) {
        int i = b * 256 + t;
        if (i < N * 4) acc[i] = 0.0f;
        return;
    }
    if (b == nzero) {
        if (t < 64) {
            int f = probe_fp32(x_all);
            if (t == 0) *flag = f;
        }
        return;
    }
    // weight blocks need the storage flag before any thread uses it -> local probe
    __shared__ int sflag;
    if (t < 64) {
        int f = probe_fp32(x_all);
        if (t == 0) sflag = f;
    }
    __syncthreads();
    int fp32m = sflag;

    if (b == nzero + 1) {
        __shared__ float wc[3][F];
        #pragma unroll
        for (int c = 0; c < 3; ++c) wc[c][t] = loadw(W_cls, c * F + t, fp32m);
        __syncthreads();
        float s0 = 0.f, s1 = 0.f, s2 = 0.f;
        for (int j = 0; j < F; ++j) {
            float ws = loadw(W_sage, t * F + j, fp32m);   // W_sage[f=t][j]
            s0 = fmaf(ws, wc[0][j], s0);
            s1 = fmaf(ws, wc[1][j], s1);
            s2 = fmaf(ws, wc[2][j], s2);
        }
        Wc2[t] = make_float4(s0, s1, s2, 0.f);
    } else {
        __shared__ float r[4][3];
        int lane = t & 63, w = t >> 6;
        float bs = loadw(b_sage, t, fp32m);
        float p0 = bs * loadw(W_cls, 0 * F + t, fp32m);
        float p1 = bs * loadw(W_cls, 1 * F + t, fp32m);
        float p2 = bs * loadw(W_cls, 2 * F + t, fp32m);
        #pragma unroll
        for (int off = 32; off > 0; off >>= 1) {
            p0 += __shfl_xor(p0, off);
            p1 += __shfl_xor(p1, off);
            p2 += __shfl_xor(p2, off);
        }
        if (lane == 0) { r[w][0] = p0; r[w][1] = p1; r[w][2] = p2; }
        __syncthreads();
        if (t < 3) bc2[t] = r[0][t] + r[1][t] + r[2][t] + r[3][t] + loadw(b_cls, t, fp32m);
    }
}

// K2: t4[n] = (x_all[n_id[n]] . Wc2, per class c=0..2). One wave per 8 nodes;
// 8 independent 1KB row reads in flight; per-lane Wc2 coeffs in registers.
__global__ __launch_bounds__(256) void tdot_kernel(
        const void* __restrict__ x_all, const int* __restrict__ n_id,
        const float4* __restrict__ Wc2, float4* __restrict__ t4,
        const int* __restrict__ flag, int N) {
    int fp32m = *flag;
    int lane = threadIdx.x & 63;
    int gw = (blockIdx.x * 256 + threadIdx.x) >> 6;
    int nw = gridDim.x * 4;

    float4 w0 = Wc2[lane * 4 + 0];
    float4 w1 = Wc2[lane * 4 + 1];
    float4 w2 = Wc2[lane * 4 + 2];
    float4 w3 = Wc2[lane * 4 + 3];

    for (int base = gw * 8; base < N; base += nw * 8) {
        int ii = base + (lane & 7);
        int idx = n_id[ii < N ? ii : (N - 1)];
        #pragma unroll
        for (int e = 0; e < 8; ++e) {
            int n = base + e;
            if (n >= N) break;
            int row = __shfl(idx, e);
            float4 v;
            if (fp32m) {
                v = ((const float4*)x_all)[(size_t)row * 64 + lane];
            } else {
                ushort4 u = ((const ushort4*)x_all)[(size_t)row * 64 + lane];
                v = make_float4(bfbits2f(u.x), bfbits2f(u.y), bfbits2f(u.z), bfbits2f(u.w));
            }
            float p0 = v.x * w0.x + v.y * w1.x + v.z * w2.x + v.w * w3.x;
            float p1 = v.x * w0.y + v.y * w1.y + v.z * w2.y + v.w * w3.y;
            float p2 = v.x * w0.z + v.y * w1.z + v.z * w2.z + v.w * w3.z;
            #pragma unroll
            for (int off = 32; off > 0; off >>= 1) {
                p0 += __shfl_xor(p0, off);
                p1 += __shfl_xor(p1, off);
                p2 += __shfl_xor(p2, off);
            }
            if (lane == 0) t4[n] = make_float4(p0, p1, p2, 0.f);
        }
    }
}

// K3: per edge: acc[dst] += (t4[src].xyz, 1). ~1.2M low-contention fp32 atomics.
__global__ void edge_kernel(const int* __restrict__ src, const int* __restrict__ dst,
                            const float4* __restrict__ t4, float* __restrict__ acc, int E) {
    int e = blockIdx.x * blockDim.x + threadIdx.x;
    if (e < E) {
        int s = src[e];
        int d = dst[e];
        float4 tv = t4[s];
        float* a = acc + (size_t)d * 4;
        atomicAdd(a + 0, tv.x);
        atomicAdd(a + 1, tv.y);
        atomicAdd(a + 2, tv.z);
        atomicAdd(a + 3, 1.0f);
    }
}

// K4: per node: scores = (t[n] + acc[n]) / (deg+1) + bc2; log_softmax; store.
__global__ void final_kernel(const float4* __restrict__ t4, const float* __restrict__ acc,
                             const float* __restrict__ bc2, void* __restrict__ out,
                             const int* __restrict__ flag, int N) {
    int fp32m = *flag;
    int n = blockIdx.x * blockDim.x + threadIdx.x;
    if (n >= N) return;
    float4 a = ((const float4*)acc)[n];
    float4 tn = t4[n];
    float inv = 1.0f / (a.w + 1.0f);
    float s0 = (tn.x + a.x) * inv + bc2[0];
    float s1 = (tn.y + a.y) * inv + bc2[1];
    float s2 = (tn.z + a.z) * inv + bc2[2];
    float mx = fmaxf(s0, fmaxf(s1, s2));
    float lse = mx + logf(expf(s0 - mx) + expf(s1 - mx) + expf(s2 - mx));
    if (fp32m) {
        float* o = (float*)out;
        o[(size_t)n * 3 + 0] = s0 - lse;
        o[(size_t)n * 3 + 1] = s1 - lse;
        o[(size_t)n * 3 + 2] = s2 - lse;
    } else {
        __hip_bfloat16* o = (__hip_bfloat16*)out;
        o[(size_t)n * 3 + 0] = __float2bfloat16(s0 - lse);
        o[(size_t)n * 3 + 1] = __float2bfloat16(s1 - lse);
        o[(size_t)n * 3 + 2] = __float2bfloat16(s2 - lse);
    }
}

extern "C" void kernel_launch(void* const* d_in, const int* in_sizes, int n_in,
                              void* d_out, int out_size, void* d_ws, size_t ws_size,
                              hipStream_t stream) {
    const void* x_all  = d_in[0];
    const int*  n_id   = (const int*)d_in[1];
    const int*  eidx   = (const int*)d_in[2];
    const void* W_sage = d_in[3];
    const void* b_sage = d_in[4];
    const void* W_cls  = d_in[5];
    const void* b_cls  = d_in[6];

    int N = in_sizes[1];
    int E = in_sizes[2] / 2;
    const int* src = eidx;
    const int* dst = eidx + E;

    // ws: t4[N] float4 (800KB) | acc[N*4] fp32 (800KB) | Wc2[256] float4 (4KB)
    //     | bc2[4] | flag[1]  -> ~1.6 MB
    float4* t4  = (float4*)d_ws;
    float*  acc = (float*)(t4 + N);
    float4* Wc2 = (float4*)(acc + (size_t)N * 4);
    float*  bc2 = (float*)(Wc2 + F);
    int*    flag = (int*)(bc2 + 4);

    int nzero = (N * 4 + 255) / 256;
    setup_kernel<<<nzero + 3, 256, 0, stream>>>(x_all, W_sage, b_sage, W_cls, b_cls,
                                                acc, Wc2, bc2, flag, N);
    int chunks = (N + 7) / 8;
    tdot_kernel<<<(chunks + 3) / 4, 256, 0, stream>>>(x_all, n_id, Wc2, t4, flag, N);
    edge_kernel<<<(E + 255) / 256, 256, 0, stream>>>(src, dst, t4, acc, E);
    final_kernel<<<(N + 255) / 256, 256, 0, stream>>>(t4, acc, bc2, d_out, flag, N);
}

// Round 8
// 221.950 us; speedup vs baseline: 7.2903x; 1.1251x over previous
//
#include <hip/hip_runtime.h>
#include <hip/hip_bf16.h>

#define F 256
#define CAP 64   // bucket capacity per node (Poisson lambda=6 -> overflow P ~ 1e-44)

__device__ __forceinline__ float bfbits2f(unsigned short u) {
    return __uint_as_float(((unsigned)u) << 16);
}
__device__ __forceinline__ float loadw(const void* __restrict__ w, int idx, int fp32m) {
    return fp32m ? ((const float*)w)[idx] : bfbits2f(((const unsigned short*)w)[idx]);
}
// fp32-vs-bf16 storage probe (r2-r7 evidence: fp32 storage, bf16-rounded values)
__device__ __forceinline__ int probe_fp32(const void* __restrict__ x_all) {
    unsigned short u = ((const unsigned short*)x_all)[(threadIdx.x & 63) * 2];
    float v = bfbits2f(u);
    unsigned long long m = __ballot(!(fabsf(v) < 100.0f));
    return (m != 0ULL) ? 1 : 0;
}

// K1: blocks [0,nz): zero cnt[N]; block nz: global flag; block nz+1: composite
// weights w{0,1,2}f[f] = sum_j W_sage[f][j]*W_cls[c][j]; block nz+2: bc2.
__global__ void setup_kernel(const void* __restrict__ x_all,
                             const void* __restrict__ W_sage, const void* __restrict__ b_sage,
                             const void* __restrict__ W_cls, const void* __restrict__ b_cls,
                             int* __restrict__ cnt, float* __restrict__ w0f,
                             float* __restrict__ w1f, float* __restrict__ w2f,
                             float* __restrict__ bc2, int* __restrict__ flag, int N) {
    int b = blockIdx.x;
    int t = threadIdx.x;
    int nz = (N + 255) / 256;
    if (b < nz) {
        int i = b * 256 + t;
        if (i < N) cnt[i] = 0;
        return;
    }
    if (b == nz) {
        if (t < 64) {
            int f = probe_fp32(x_all);
            if (t == 0) *flag = f;
        }
        return;
    }
    __shared__ int sflag;
    if (t < 64) {
        int f = probe_fp32(x_all);
        if (t == 0) sflag = f;
    }
    __syncthreads();
    int fp32m = sflag;

    if (b == nz + 1) {
        __shared__ float wc[3][F];
        #pragma unroll
        for (int c = 0; c < 3; ++c) wc[c][t] = loadw(W_cls, c * F + t, fp32m);
        __syncthreads();
        float s0 = 0.f, s1 = 0.f, s2 = 0.f;
        for (int j = 0; j < F; ++j) {
            float ws = loadw(W_sage, t * F + j, fp32m);
            s0 = fmaf(ws, wc[0][j], s0);
            s1 = fmaf(ws, wc[1][j], s1);
            s2 = fmaf(ws, wc[2][j], s2);
        }
        w0f[t] = s0; w1f[t] = s1; w2f[t] = s2;
    } else {
        __shared__ float r[4][3];
        int lane = t & 63, w = t >> 6;
        float bs = loadw(b_sage, t, fp32m);
        float p0 = bs * loadw(W_cls, 0 * F + t, fp32m);
        float p1 = bs * loadw(W_cls, 1 * F + t, fp32m);
        float p2 = bs * loadw(W_cls, 2 * F + t, fp32m);
        #pragma unroll
        for (int off = 32; off > 0; off >>= 1) {
            p0 += __shfl_xor(p0, off);
            p1 += __shfl_xor(p1, off);
            p2 += __shfl_xor(p2, off);
        }
        if (lane == 0) { r[w][0] = p0; r[w][1] = p1; r[w][2] = p2; }
        __syncthreads();
        if (t < 3) bc2[t] = r[0][t] + r[1][t] + r[2][t] + r[3][t] + loadw(b_cls, t, fp32m);
    }
}

// K2: blocks [0,nTall): streaming tall[r] = x_all[r].Wc2 for ALL rows, lane-per-row
//     (sequential 102 MB sweep, no gather). blocks [nTall,..): bucket fill with
//     resolved row ids (bkt[d][p] = n_id[src]).
__global__ __launch_bounds__(256) void stream_fill_kernel(
        const void* __restrict__ x_all, const int* __restrict__ n_id,
        const int* __restrict__ src, const int* __restrict__ dst,
        const float* __restrict__ w0f, const float* __restrict__ w1f,
        const float* __restrict__ w2f,
        float4* __restrict__ tall, int* __restrict__ cnt, int* __restrict__ bkt,
        const int* __restrict__ flag, int R, int E, int nTall) {
    int b = blockIdx.x;
    int t = threadIdx.x;
    if (b < nTall) {
        int fp32m = *flag;
        __shared__ __align__(16) float sw0[F], sw1[F], sw2[F];
        sw0[t] = w0f[t]; sw1[t] = w1f[t]; sw2[t] = w2f[t];
        __syncthreads();
        const float4* sw04 = (const float4*)sw0;
        const float4* sw14 = (const float4*)sw1;
        const float4* sw24 = (const float4*)sw2;

        int row = b * 256 + t;   // lane-per-row: wave reads 64 consecutive rows
        if (row >= R) return;
        float a0 = 0.f, a1 = 0.f, a2 = 0.f;
        if (fp32m) {
            const float4* xr = (const float4*)((const float*)x_all + (size_t)row * F);
            #pragma unroll 8
            for (int j = 0; j < 64; ++j) {
                float4 v = xr[j];
                float4 u0 = sw04[j], u1 = sw14[j], u2 = sw24[j];
                a0 += v.x * u0.x + v.y * u0.y + v.z * u0.z + v.w * u0.w;
                a1 += v.x * u1.x + v.y * u1.y + v.z * u1.z + v.w * u1.w;
                a2 += v.x * u2.x + v.y * u2.y + v.z * u2.z + v.w * u2.w;
            }
        } else {
            const uint4* xr = (const uint4*)((const unsigned short*)x_all + (size_t)row * F);
            #pragma unroll 4
            for (int j = 0; j < 32; ++j) {   // 8 bf16 per step
                uint4 q = xr[j];
                float4 u0a = sw04[2 * j], u0b = sw04[2 * j + 1];
                float4 u1a = sw14[2 * j], u1b = sw14[2 * j + 1];
                float4 u2a = sw24[2 * j], u2b = sw24[2 * j + 1];
                float v0 = bfbits2f((unsigned short)(q.x & 0xffff));
                float v1 = bfbits2f((unsigned short)(q.x >> 16));
                float v2 = bfbits2f((unsigned short)(q.y & 0xffff));
                float v3 = bfbits2f((unsigned short)(q.y >> 16));
                float v4 = bfbits2f((unsigned short)(q.z & 0xffff));
                float v5 = bfbits2f((unsigned short)(q.z >> 16));
                float v6 = bfbits2f((unsigned short)(q.w & 0xffff));
                float v7 = bfbits2f((unsigned short)(q.w >> 16));
                a0 += v0*u0a.x + v1*u0a.y + v2*u0a.z + v3*u0a.w
                    + v4*u0b.x + v5*u0b.y + v6*u0b.z + v7*u0b.w;
                a1 += v0*u1a.x + v1*u1a.y + v2*u1a.z + v3*u1a.w
                    + v4*u1b.x + v5*u1b.y + v6*u1b.z + v7*u1b.w;
                a2 += v0*u2a.x + v1*u2a.y + v2*u2a.z + v3*u2a.w
                    + v4*u2b.x + v5*u2b.y + v6*u2b.z + v7*u2b.w;
            }
        }
        tall[row] = make_float4(a0, a1, a2, 0.f);
    } else {
        int e = (b - nTall) * 256 + t;
        if (e < E) {
            int s = src[e];
            int d = dst[e];
            int rid = n_id[s];                       // resolve row id now (L2-resident)
            int p = atomicAdd(&cnt[d], 1);
            if (p < CAP) bkt[((size_t)d << 6) + p] = rid;
        }
    }
}

// K3: thread-per-node: sum tall over {self, neighbors}, /(deg+1), +bc2, log_softmax.
__global__ void final_kernel(const float4* __restrict__ tall, const int* __restrict__ n_id,
                             const int* __restrict__ cnt, const int* __restrict__ bkt,
                             const float* __restrict__ bc2, void* __restrict__ out,
                             const int* __restrict__ flag, int N) {
    int fp32m = *flag;
    int n = blockIdx.x * blockDim.x + threadIdx.x;
    if (n >= N) return;
    int dt = cnt[n];
    int d = dt < CAP ? dt : CAP;
    const int* bk = bkt + ((size_t)n << 6);
    float4 tv = tall[n_id[n]];
    float a0 = tv.x, a1 = tv.y, a2 = tv.z;
    for (int e = 0; e < d; e += 4) {
        int rem = d - e;
        int i0 = bk[e];
        int i1 = (rem > 1) ? bk[e + 1] : i0;
        int i2 = (rem > 2) ? bk[e + 2] : i0;
        int i3 = (rem > 3) ? bk[e + 3] : i0;
        float4 v0 = tall[i0];
        float4 v1 = tall[i1];
        float4 v2 = tall[i2];
        float4 v3 = tall[i3];
        a0 += v0.x; a1 += v0.y; a2 += v0.z;
        if (rem > 1) { a0 += v1.x; a1 += v1.y; a2 += v1.z; }
        if (rem > 2) { a0 += v2.x; a1 += v2.y; a2 += v2.z; }
        if (rem > 3) { a0 += v3.x; a1 += v3.y; a2 += v3.z; }
    }
    float inv = 1.0f / (float)(dt + 1);
    float s0 = a0 * inv + bc2[0];
    float s1 = a1 * inv + bc2[1];
    float s2 = a2 * inv + bc2[2];
    float mx = fmaxf(s0, fmaxf(s1, s2));
    float lse = mx + logf(expf(s0 - mx) + expf(s1 - mx) + expf(s2 - mx));
    if (fp32m) {
        float* o = (float*)out;
        o[(size_t)n * 3 + 0] = s0 - lse;
        o[(size_t)n * 3 + 1] = s1 - lse;
        o[(size_t)n * 3 + 2] = s2 - lse;
    } else {
        __hip_bfloat16* o = (__hip_bfloat16*)out;
        o[(size_t)n * 3 + 0] = __float2bfloat16(s0 - lse);
        o[(size_t)n * 3 + 1] = __float2bfloat16(s1 - lse);
        o[(size_t)n * 3 + 2] = __float2bfloat16(s2 - lse);
    }
}

extern "C" void kernel_launch(void* const* d_in, const int* in_sizes, int n_in,
                              void* d_out, int out_size, void* d_ws, size_t ws_size,
                              hipStream_t stream) {
    const void* x_all  = d_in[0];
    const int*  n_id   = (const int*)d_in[1];
    const int*  eidx   = (const int*)d_in[2];
    const void* W_sage = d_in[3];
    const void* b_sage = d_in[4];
    const void* W_cls  = d_in[5];
    const void* b_cls  = d_in[6];

    int R = in_sizes[0] / F;        // N_ALL = 100000
    int N = in_sizes[1];            // 50000
    int E = in_sizes[2] / 2;        // 300000
    const int* src = eidx;
    const int* dst = eidx + E;

    // ws: tall[R] float4 (1.6MB) | cnt[N] (200KB) | bkt[N*64] (12.8MB)
    //     | w0f/w1f/w2f[256] | bc2[4] | flag[1]   -> ~14.6 MB
    float4* tall = (float4*)d_ws;
    int* cnt  = (int*)(tall + R);
    int* bkt  = cnt + N;
    float* w0f = (float*)(bkt + ((size_t)N << 6));
    float* w1f = w0f + F;
    float* w2f = w1f + F;
    float* bc2 = w2f + F;
    int* flag  = (int*)(bc2 + 4);

    int nz = (N + 255) / 256;
    setup_kernel<<<nz + 3, 256, 0, stream>>>(x_all, W_sage, b_sage, W_cls, b_cls,
                                             cnt, w0f, w1f, w2f, bc2, flag, N);
    int nTall = (R + 255) / 256;
    int nFill = (E + 255) / 256;
    stream_fill_kernel<<<nTall + nFill, 256, 0, stream>>>(
        x_all, n_id, src, dst, w0f, w1f, w2f, tall, cnt, bkt, flag, R, E, nTall);
    final_kernel<<<(N + 255) / 256, 256, 0, stream>>>(tall, n_id, cnt, bkt, bc2,
                                                      d_out, flag, N);
}